// Round 1
// baseline (509.407 us; speedup 1.0000x reference)
//
#include <hip/hip_runtime.h>

#define HW2   96
#define NH    12
#define HC    16
#define LPIX  (HW2*HW2)      // 9216
#define CDIM  192
#define BATCH 4

// Out[r, col0+c] = (sum_k X[r,k]*Wc[c,k] + bias[c]) * smul   for c in [0,96)
// X row-major with leading dim = KDIM. Wc is a (96, KDIM) row-major chunk.
template<int KDIM>
__global__ __launch_bounds__(256) void gemm_kernel(
    const float* __restrict__ X,
    const float* __restrict__ Wc,
    const float* __restrict__ bias,
    float base_scale,
    const float* __restrict__ scale_ptr,
    float* __restrict__ Out, int ldo, int col0)
{
  constexpr int KP = KDIM + 4;               // LDS pad to break bank conflicts
  __shared__ float xs[64 * KP];
  const int tid = threadIdx.x;
  const int r0  = blockIdx.x * 64;

  // stage 64 rows of X (contiguous 64*KDIM floats) into LDS
  const float* xsrc = X + (size_t)r0 * KDIM;
  for (int i = tid * 4; i < 64 * KDIM; i += 1024) {
    float4 v = *(const float4*)(xsrc + i);
    int row = i / KDIM, c = i - row * KDIM;
    *(float4*)&xs[row * KP + c] = v;
  }
  __syncthreads();

  const int tx = tid & 15, ty = tid >> 4;    // 16 x 16 thread tile
  float acc[4][6];
  #pragma unroll
  for (int i = 0; i < 4; i++)
    #pragma unroll
    for (int j = 0; j < 6; j++) acc[i][j] = 0.f;

  for (int k = 0; k < KDIM; k += 4) {
    float4 xf[4], wf[6];
    #pragma unroll
    for (int i = 0; i < 4; i++)
      xf[i] = *(const float4*)&xs[(ty + 16 * i) * KP + k];
    #pragma unroll
    for (int j = 0; j < 6; j++)
      wf[j] = *(const float4*)&Wc[(size_t)(tx + 16 * j) * KDIM + k];
    #pragma unroll
    for (int i = 0; i < 4; i++)
      #pragma unroll
      for (int j = 0; j < 6; j++) {
        acc[i][j] = fmaf(xf[i].x, wf[j].x, acc[i][j]);
        acc[i][j] = fmaf(xf[i].y, wf[j].y, acc[i][j]);
        acc[i][j] = fmaf(xf[i].z, wf[j].z, acc[i][j]);
        acc[i][j] = fmaf(xf[i].w, wf[j].w, acc[i][j]);
      }
  }

  float smul = base_scale;
  if (scale_ptr) smul *= scale_ptr[0];
  #pragma unroll
  for (int j = 0; j < 6; j++) {
    float bj = bias[tx + 16 * j];
    #pragma unroll
    for (int i = 0; i < 4; i++) {
      int r = r0 + ty + 16 * i;
      Out[(size_t)r * ldo + col0 + tx + 16 * j] = (acc[i][j] + bj) * smul;
    }
  }
}

// One thread per (b, l, n). Reads q (16f) + 9 neighbors' k/v (16f each),
// softmax over 9 (zero-padded neighbors score exactly 0), writes out2 in
// place over q (this thread is the only reader of that q chunk).
__global__ __launch_bounds__(256) void attn_kernel(
    float* __restrict__ Qbuf, const float* __restrict__ KVbuf,
    const float* __restrict__ fkr_p, const float* __restrict__ fvr_p)
{
  int t  = blockIdx.x * 256 + threadIdx.x;
  int n  = t % NH;
  int bl = t / NH;                 // b*9216 + l
  int l  = bl % LPIX;
  int b  = bl / LPIX;
  int h2 = l / HW2, w2 = l - h2 * HW2;
  float fkr = fkr_p[0], fvr = fvr_p[0];

  float* qp = Qbuf + (size_t)bl * CDIM + n * HC;
  float4 q0 = *(const float4*)(qp + 0);
  float4 q1 = *(const float4*)(qp + 4);
  float4 q2 = *(const float4*)(qp + 8);
  float4 q3 = *(const float4*)(qp + 12);

  const float* kvb = KVbuf + (size_t)b * (LPIX * 384) + n * HC;

  float sc[9];
  int   nb[9];
  #pragma unroll
  for (int kk = 0; kk < 9; kk++) {
    int hh = h2 + kk / 3 - 1;
    int ww = w2 + kk % 3 - 1;
    bool ok = ((unsigned)hh < (unsigned)HW2) && ((unsigned)ww < (unsigned)HW2);
    nb[kk] = ok ? (hh * HW2 + ww) * 384 : -1;
    float s = 0.f;
    if (ok) {
      const float* kp = kvb + nb[kk];
      float4 k0 = *(const float4*)(kp + 0);
      float4 k1 = *(const float4*)(kp + 4);
      float4 k2 = *(const float4*)(kp + 8);
      float4 k3 = *(const float4*)(kp + 12);
      s  = q0.x*k0.x + q0.y*k0.y + q0.z*k0.z + q0.w*k0.w;
      s += q1.x*k1.x + q1.y*k1.y + q1.z*k1.z + q1.w*k1.w;
      s += q2.x*k2.x + q2.y*k2.y + q2.z*k2.z + q2.w*k2.w;
      s += q3.x*k3.x + q3.y*k3.y + q3.z*k3.z + q3.w*k3.w;
      s *= fkr;
    }
    sc[kk] = s;
  }

  float m = sc[0];
  #pragma unroll
  for (int kk = 1; kk < 9; kk++) m = fmaxf(m, sc[kk]);
  float ssum = 0.f;
  #pragma unroll
  for (int kk = 0; kk < 9; kk++) {
    float e = __expf(sc[kk] - m);
    sc[kk] = e;
    ssum += e;
  }

  float4 a0 = {0,0,0,0}, a1 = a0, a2 = a0, a3 = a0;
  #pragma unroll
  for (int kk = 0; kk < 9; kk++) {
    if (nb[kk] >= 0) {
      const float* vp = kvb + nb[kk] + 192;
      float w = sc[kk];
      float4 v0 = *(const float4*)(vp + 0);
      float4 v1 = *(const float4*)(vp + 4);
      float4 v2 = *(const float4*)(vp + 8);
      float4 v3 = *(const float4*)(vp + 12);
      a0.x = fmaf(w, v0.x, a0.x); a0.y = fmaf(w, v0.y, a0.y);
      a0.z = fmaf(w, v0.z, a0.z); a0.w = fmaf(w, v0.w, a0.w);
      a1.x = fmaf(w, v1.x, a1.x); a1.y = fmaf(w, v1.y, a1.y);
      a1.z = fmaf(w, v1.z, a1.z); a1.w = fmaf(w, v1.w, a1.w);
      a2.x = fmaf(w, v2.x, a2.x); a2.y = fmaf(w, v2.y, a2.y);
      a2.z = fmaf(w, v2.z, a2.z); a2.w = fmaf(w, v2.w, a2.w);
      a3.x = fmaf(w, v3.x, a3.x); a3.y = fmaf(w, v3.y, a3.y);
      a3.z = fmaf(w, v3.z, a3.z); a3.w = fmaf(w, v3.w, a3.w);
    }
  }
  float r = fvr / ssum;
  a0.x *= r; a0.y *= r; a0.z *= r; a0.w *= r;
  a1.x *= r; a1.y *= r; a1.z *= r; a1.w *= r;
  a2.x *= r; a2.y *= r; a2.z *= r; a2.w *= r;
  a3.x *= r; a3.y *= r; a3.z *= r; a3.w *= r;
  *(float4*)(qp + 0)  = a0;
  *(float4*)(qp + 4)  = a1;
  *(float4*)(qp + 8)  = a2;
  *(float4*)(qp + 12) = a3;
}

extern "C" void kernel_launch(void* const* d_in, const int* in_sizes, int n_in,
                              void* d_out, int out_size, void* d_ws, size_t ws_size,
                              hipStream_t stream) {
  const float* x   = (const float*)d_in[0];
  const float* Wq  = (const float*)d_in[1];
  const float* bq  = (const float*)d_in[2];
  const float* Wkv = (const float*)d_in[3];
  const float* bkv = (const float*)d_in[4];
  const float* Wp  = (const float*)d_in[5];
  const float* bp  = (const float*)d_in[6];
  const float* fqr = (const float*)d_in[7];
  const float* fkr = (const float*)d_in[8];
  const float* fvr = (const float*)d_in[9];

  float* Qbuf  = (float*)d_ws;                          // 7,077,888 floats
  float* KVbuf = Qbuf + (size_t)BATCH * LPIX * CDIM;    // 14,155,776 floats
  float* out   = (float*)d_out;

  const float qscale = 0.07216878364870322f;            // 192^-0.5

  // Q = X * Wq^T  (73728 x 96 rows; row = (b,c,h))
  gemm_kernel<96><<<dim3(1152), dim3(256), 0, stream>>>(
      x, Wq, bq, qscale, fqr, Qbuf, 96, 0);
  // KV cols 0..95 and 96..191
  gemm_kernel<96><<<dim3(1152), dim3(256), 0, stream>>>(
      x, Wkv, bkv, 1.0f, (const float*)nullptr, KVbuf, 192, 0);
  gemm_kernel<96><<<dim3(1152), dim3(256), 0, stream>>>(
      x, Wkv + 96 * 96, bkv + 96, 1.0f, (const float*)nullptr, KVbuf, 192, 96);

  // attention: 4*9216*12 threads
  attn_kernel<<<dim3(1728), dim3(256), 0, stream>>>(Qbuf, KVbuf, fkr, fvr);

  // proj: (36864 x 192) * Wp^T + bp -> d_out
  gemm_kernel<192><<<dim3(576), dim3(256), 0, stream>>>(
      Qbuf, Wp, bp, 1.0f, (const float*)nullptr, out, 192, 0);
  gemm_kernel<192><<<dim3(576), dim3(256), 0, stream>>>(
      Qbuf, Wp + 96 * 192, bp + 96, 1.0f, (const float*)nullptr, out, 192, 96);
}

// Round 2
// 88.357 us; speedup vs baseline: 5.7654x; 5.7654x over previous
//
#include <hip/hip_runtime.h>

#define HW2   96
#define NH    12
#define LPIX  (HW2*HW2)      // 9216
#define BATCH 4

typedef __attribute__((ext_vector_type(8))) short bf16x8;
typedef __attribute__((ext_vector_type(4))) float f32x4;

static __device__ __forceinline__ float bf2f(unsigned short u) {
  union { unsigned int i; float f; } v; v.i = ((unsigned int)u) << 16; return v.f;
}
static __device__ __forceinline__ unsigned short f2bf(float f) {
  union { float f; unsigned int i; } v; v.f = f;
  unsigned int r = v.i + 0x7FFF + ((v.i >> 16) & 1);   // round-nearest-even
  return (unsigned short)(r >> 16);
}

// ---- tiny: convert the three weight matrices to bf16 ----------------------
__global__ __launch_bounds__(256) void cvt_w_kernel(
    const float* __restrict__ Wq, const float* __restrict__ Wkv,
    const float* __restrict__ Wp,
    unsigned short* __restrict__ wqb, unsigned short* __restrict__ wkvb,
    unsigned short* __restrict__ wpb) {
  int i = blockIdx.x * 256 + threadIdx.x;
  if (i < 9216)       wqb[i]          = f2bf(Wq[i]);
  else if (i < 27648) wkvb[i - 9216]  = f2bf(Wkv[i - 9216]);
  else if (i < 64512) wpb[i - 27648]  = f2bf(Wp[i - 27648]);
}

// ---- fused Q+KV GEMM: rows r=(b,c,h) of X(73728x96), N=96(Q)+192(KV) ------
// Q written fp32 (scaled by 192^-0.5 * f_qr); KV written bf16, rows with
// even parity (h even => K) scaled by f_kr, odd (V) by f_vr.
__global__ __launch_bounds__(256) void qkv_gemm(
    const float* __restrict__ X,
    const unsigned short* __restrict__ wq, const unsigned short* __restrict__ wkv,
    const float* __restrict__ bq, const float* __restrict__ bkv,
    const float* __restrict__ fqr, const float* __restrict__ fkr,
    const float* __restrict__ fvr,
    float* __restrict__ Qbuf, unsigned short* __restrict__ KVb)
{
  __shared__ unsigned short xs[64 * 120];      // 64 rows, K=96 padded to 120
  const int tid = threadIdx.x;
  const int r0  = blockIdx.x * 64;

  // stage 64x96 fp32 -> bf16 LDS (source fully coalesced float4)
  const float4* xsrc = (const float4*)(X + (size_t)r0 * 96);
  #pragma unroll
  for (int it = 0; it < 6; it++) {
    int c = tid + it * 256;                    // 1536 float4 chunks
    float4 v = xsrc[c];
    int row = c / 24, col = (c % 24) * 4;
    ushort4 p;
    p.x = f2bf(v.x); p.y = f2bf(v.y); p.z = f2bf(v.z); p.w = f2bf(v.w);
    *(ushort4*)&xs[row * 120 + col] = p;
  }
  __syncthreads();

  const int lane = tid & 63, w = tid >> 6;
  const int col  = lane & 15;
  const int koff = (lane >> 4) * 8;
  const int arow = 16 * w + (lane & 15);
  const int rbase = r0 + 16 * w + 4 * (lane >> 4);

  bf16x8 af0 = *(const bf16x8*)&xs[arow * 120 + koff];
  bf16x8 af1 = *(const bf16x8*)&xs[arow * 120 + koff + 32];
  bf16x8 af2 = *(const bf16x8*)&xs[arow * 120 + koff + 64];

  const float fqr0 = fqr[0] * 0.07216878364870322f;
  const float fkr0 = fkr[0], fvr0 = fvr[0];

  #pragma unroll
  for (int nt = 0; nt < 18; nt++) {
    const unsigned short* wrow = (nt < 6)
        ? wq  + (size_t)(nt * 16 + col) * 96 + koff
        : wkv + (size_t)((nt - 6) * 16 + col) * 96 + koff;
    bf16x8 b0 = *(const bf16x8*)(wrow);
    bf16x8 b1 = *(const bf16x8*)(wrow + 32);
    bf16x8 b2 = *(const bf16x8*)(wrow + 64);
    f32x4 acc = {0.f, 0.f, 0.f, 0.f};
    acc = __builtin_amdgcn_mfma_f32_16x16x32_bf16(af0, b0, acc, 0, 0, 0);
    acc = __builtin_amdgcn_mfma_f32_16x16x32_bf16(af1, b1, acc, 0, 0, 0);
    acc = __builtin_amdgcn_mfma_f32_16x16x32_bf16(af2, b2, acc, 0, 0, 0);

    if (nt < 6) {
      int u = nt * 16 + col;
      float bias = bq[u];
      #pragma unroll
      for (int i = 0; i < 4; i++)
        Qbuf[(size_t)(rbase + i) * 96 + u] = (acc[i] + bias) * fqr0;
    } else {
      int u = (nt - 6) * 16 + col;
      float bias = bkv[u];
      #pragma unroll
      for (int i = 0; i < 4; i++) {
        int r = rbase + i;
        float s = (r & 1) ? fvr0 : fkr0;     // h parity == r parity (96 even)
        KVb[(size_t)r * 192 + u] = f2bf((acc[i] + bias) * s);
      }
    }
  }
}

// ---- attention: one thread per (b,l,n); scalar-free (scales folded) -------
__global__ __launch_bounds__(256) void attn_kernel(
    const float* __restrict__ Qbuf, const unsigned short* __restrict__ KVb,
    unsigned short* __restrict__ out2)
{
  int t  = blockIdx.x * 256 + threadIdx.x;
  int n  = t % NH;
  int bl = t / NH;
  int l  = bl % LPIX;
  int b  = bl / LPIX;
  int h2 = l / HW2, w2 = l - h2 * HW2;

  const float* qp = Qbuf + (size_t)bl * 192 + n * 16;
  float q[16];
  *(float4*)&q[0]  = *(const float4*)(qp + 0);
  *(float4*)&q[4]  = *(const float4*)(qp + 4);
  *(float4*)&q[8]  = *(const float4*)(qp + 8);
  *(float4*)&q[12] = *(const float4*)(qp + 12);

  const unsigned short* kvb = KVb + (size_t)b * (LPIX * 384) + n * 16;

  float sc[9];
  int   nb[9];
  #pragma unroll
  for (int kk = 0; kk < 9; kk++) {
    int hh = h2 + kk / 3 - 1;
    int ww = w2 + kk % 3 - 1;
    bool ok = ((unsigned)hh < (unsigned)HW2) && ((unsigned)ww < (unsigned)HW2);
    nb[kk] = ok ? (hh * HW2 + ww) * 384 : -1;
    float s = 0.f;
    if (ok) {
      const unsigned short* kp = kvb + nb[kk];
      unsigned short kd[16];
      *(uint4*)&kd[0] = *(const uint4*)(kp);
      *(uint4*)&kd[8] = *(const uint4*)(kp + 8);
      #pragma unroll
      for (int j = 0; j < 16; j++) s = fmaf(q[j], bf2f(kd[j]), s);
    }
    sc[kk] = s;
  }

  float m = sc[0];
  #pragma unroll
  for (int kk = 1; kk < 9; kk++) m = fmaxf(m, sc[kk]);
  float ssum = 0.f;
  #pragma unroll
  for (int kk = 0; kk < 9; kk++) {
    float e = __expf(sc[kk] - m);
    sc[kk] = e;
    ssum += e;
  }

  float acc[16];
  #pragma unroll
  for (int j = 0; j < 16; j++) acc[j] = 0.f;
  #pragma unroll
  for (int kk = 0; kk < 9; kk++) {
    if (nb[kk] >= 0) {
      const unsigned short* vp = kvb + nb[kk] + 192;
      unsigned short vd[16];
      *(uint4*)&vd[0] = *(const uint4*)(vp);
      *(uint4*)&vd[8] = *(const uint4*)(vp + 8);
      float wgt = sc[kk];
      #pragma unroll
      for (int j = 0; j < 16; j++) acc[j] = fmaf(wgt, bf2f(vd[j]), acc[j]);
    }
  }
  float rinv = 1.f / ssum;
  unsigned short od[16];
  #pragma unroll
  for (int j = 0; j < 16; j++) od[j] = f2bf(acc[j] * rinv);
  unsigned short* op = out2 + (size_t)bl * 192 + n * 16;
  *(uint4*)(op)     = *(uint4*)&od[0];
  *(uint4*)(op + 8) = *(uint4*)&od[8];
}

// ---- proj GEMM: out2(36864x192 bf16) x Wp^T(192x192) + bp -> d_out fp32 ---
__global__ __launch_bounds__(256) void proj_gemm(
    const unsigned short* __restrict__ A, const unsigned short* __restrict__ wp,
    const float* __restrict__ bp, float* __restrict__ Out)
{
  __shared__ unsigned short xs[64 * 200];      // 64 rows, K=192 padded to 200
  const int tid = threadIdx.x;
  const int r0  = blockIdx.x * 64;

  const unsigned short* asrc = A + (size_t)r0 * 192;
  #pragma unroll
  for (int it = 0; it < 6; it++) {
    int c = tid + it * 256;                    // 1536 ushort8 chunks
    int row = c / 24, col = (c % 24) * 8;
    *(bf16x8*)&xs[row * 200 + col] = *(const bf16x8*)(asrc + c * 8);
  }
  __syncthreads();

  const int lane = tid & 63, w = tid >> 6;
  const int col  = lane & 15;
  const int koff = (lane >> 4) * 8;
  const int arow = 16 * w + (lane & 15);
  const int rbase = r0 + 16 * w + 4 * (lane >> 4);

  bf16x8 af[6];
  #pragma unroll
  for (int kt = 0; kt < 6; kt++)
    af[kt] = *(const bf16x8*)&xs[arow * 200 + koff + kt * 32];

  #pragma unroll
  for (int nt = 0; nt < 12; nt++) {
    const unsigned short* wrow = wp + (size_t)(nt * 16 + col) * 192 + koff;
    f32x4 acc = {0.f, 0.f, 0.f, 0.f};
    #pragma unroll
    for (int kt = 0; kt < 6; kt++) {
      bf16x8 bfr = *(const bf16x8*)(wrow + kt * 32);
      acc = __builtin_amdgcn_mfma_f32_16x16x32_bf16(af[kt], bfr, acc, 0, 0, 0);
    }
    int u = nt * 16 + col;
    float bias = bp[u];
    #pragma unroll
    for (int i = 0; i < 4; i++)
      Out[(size_t)(rbase + i) * 192 + u] = acc[i] + bias;
  }
}

extern "C" void kernel_launch(void* const* d_in, const int* in_sizes, int n_in,
                              void* d_out, int out_size, void* d_ws, size_t ws_size,
                              hipStream_t stream) {
  const float* x   = (const float*)d_in[0];
  const float* Wq  = (const float*)d_in[1];
  const float* bq  = (const float*)d_in[2];
  const float* Wkv = (const float*)d_in[3];
  const float* bkv = (const float*)d_in[4];
  const float* Wp  = (const float*)d_in[5];
  const float* bp  = (const float*)d_in[6];
  const float* fqr = (const float*)d_in[7];
  const float* fkr = (const float*)d_in[8];
  const float* fvr = (const float*)d_in[9];

  char* ws = (char*)d_ws;
  float*          Qbuf = (float*)ws;                          // 28,311,552 B
  unsigned short* KVb  = (unsigned short*)(ws + 28311552);    // 28,311,552 B
  unsigned short* out2 = (unsigned short*)(ws + 56623104);    // 14,155,776 B
  unsigned short* wqb  = (unsigned short*)(ws + 70778880);    //     18,432 B
  unsigned short* wkvb = (unsigned short*)(ws + 70797312);    //     36,864 B
  unsigned short* wpb  = (unsigned short*)(ws + 70834176);    //     73,728 B

  cvt_w_kernel<<<dim3(252), dim3(256), 0, stream>>>(Wq, Wkv, Wp, wqb, wkvb, wpb);

  qkv_gemm<<<dim3(1152), dim3(256), 0, stream>>>(
      x, wqb, wkvb, bq, bkv, fqr, fkr, fvr, Qbuf, KVb);

  attn_kernel<<<dim3(1728), dim3(256), 0, stream>>>(Qbuf, KVb, out2);

  proj_gemm<<<dim3(576), dim3(256), 0, stream>>>(out2, wpb, bp, (float*)d_out);
}

// Round 3
// 85.536 us; speedup vs baseline: 5.9555x; 1.0330x over previous
//
#include <hip/hip_runtime.h>

#define HW2   96
#define NH    12
#define LPIX  (HW2*HW2)      // 9216
#define BATCH 4

typedef __attribute__((ext_vector_type(8))) short bf16x8;
typedef __attribute__((ext_vector_type(4))) float f32x4;

static __device__ __forceinline__ float bf2f(unsigned short u) {
  union { unsigned int i; float f; } v; v.i = ((unsigned int)u) << 16; return v.f;
}
static __device__ __forceinline__ unsigned short f2bf(float f) {
  union { float f; unsigned int i; } v; v.f = f;
  unsigned int r = v.i + 0x7FFF + ((v.i >> 16) & 1);   // round-nearest-even
  return (unsigned short)(r >> 16);
}

// ---- tiny: convert the three weight matrices to bf16 ----------------------
__global__ __launch_bounds__(256) void cvt_w_kernel(
    const float* __restrict__ Wq, const float* __restrict__ Wkv,
    const float* __restrict__ Wp,
    unsigned short* __restrict__ wqb, unsigned short* __restrict__ wkvb,
    unsigned short* __restrict__ wpb) {
  int i = blockIdx.x * 256 + threadIdx.x;
  if (i < 9216)       wqb[i]          = f2bf(Wq[i]);
  else if (i < 27648) wkvb[i - 9216]  = f2bf(Wkv[i - 9216]);
  else if (i < 64512) wpb[i - 27648]  = f2bf(Wp[i - 27648]);
}

// ---- fused Q+KV GEMM: rows r=(b,c,h) of X(73728x96), N=96(Q)+192(KV) ------
// Q written bf16 (scaled by 192^-0.5 * f_qr); KV written bf16; row parity
// (i&1) selects f_kr (K, even) vs f_vr (V, odd). Epilogue goes through LDS
// so all global stores are coalesced 16B.
__global__ __launch_bounds__(256) void qkv_gemm(
    const float* __restrict__ X,
    const unsigned short* __restrict__ wq, const unsigned short* __restrict__ wkv,
    const float* __restrict__ bq, const float* __restrict__ bkv,
    const float* __restrict__ fqr, const float* __restrict__ fkr,
    const float* __restrict__ fvr,
    unsigned short* __restrict__ Qb, unsigned short* __restrict__ KVb)
{
  // phase 1: staging buffer 64x120 (7680) ; phase 2: Q tile 64x104 (6656)
  //          + KV tile 64x200 (12800) = 19456 ushorts
  __shared__ unsigned short lds[19456];
  unsigned short* xs  = lds;            // stride 120
  unsigned short* qo  = lds;            // stride 104
  unsigned short* kvo = lds + 6656;     // stride 200

  const int tid = threadIdx.x;
  const int r0  = blockIdx.x * 64;

  // stage 64x96 fp32 -> bf16 LDS (source fully coalesced float4)
  const float4* xsrc = (const float4*)(X + (size_t)r0 * 96);
  #pragma unroll
  for (int it = 0; it < 6; it++) {
    int c = tid + it * 256;                    // 1536 float4 chunks
    float4 v = xsrc[c];
    int row = c / 24, col = (c % 24) * 4;
    ushort4 p;
    p.x = f2bf(v.x); p.y = f2bf(v.y); p.z = f2bf(v.z); p.w = f2bf(v.w);
    *(ushort4*)&xs[row * 120 + col] = p;
  }
  __syncthreads();

  const int lane = tid & 63, w = tid >> 6;
  const int col  = lane & 15;
  const int koff = (lane >> 4) * 8;
  const int arow = 16 * w + (lane & 15);
  const int rloc = 16 * w + 4 * (lane >> 4);   // local row base of acc

  bf16x8 af0 = *(const bf16x8*)&xs[arow * 120 + koff];
  bf16x8 af1 = *(const bf16x8*)&xs[arow * 120 + koff + 32];
  bf16x8 af2 = *(const bf16x8*)&xs[arow * 120 + koff + 64];
  __syncthreads();                             // xs dead; reuse as qo/kvo

  const float fqr0 = fqr[0] * 0.07216878364870322f;
  const float fkr0 = fkr[0], fvr0 = fvr[0];

  #pragma unroll
  for (int nt = 0; nt < 18; nt++) {
    const unsigned short* wrow = (nt < 6)
        ? wq  + (size_t)(nt * 16 + col) * 96 + koff
        : wkv + (size_t)((nt - 6) * 16 + col) * 96 + koff;
    bf16x8 b0 = *(const bf16x8*)(wrow);
    bf16x8 b1 = *(const bf16x8*)(wrow + 32);
    bf16x8 b2 = *(const bf16x8*)(wrow + 64);
    f32x4 acc = {0.f, 0.f, 0.f, 0.f};
    acc = __builtin_amdgcn_mfma_f32_16x16x32_bf16(af0, b0, acc, 0, 0, 0);
    acc = __builtin_amdgcn_mfma_f32_16x16x32_bf16(af1, b1, acc, 0, 0, 0);
    acc = __builtin_amdgcn_mfma_f32_16x16x32_bf16(af2, b2, acc, 0, 0, 0);

    if (nt < 6) {
      int u = nt * 16 + col;
      float bias = bq[u];
      #pragma unroll
      for (int i = 0; i < 4; i++)
        qo[(rloc + i) * 104 + u] = f2bf((acc[i] + bias) * fqr0);
    } else {
      int u = (nt - 6) * 16 + col;
      float bias = bkv[u];
      #pragma unroll
      for (int i = 0; i < 4; i++) {
        float s = (i & 1) ? fvr0 : fkr0;       // row parity: even=K, odd=V
        kvo[(rloc + i) * 200 + u] = f2bf((acc[i] + bias) * s);
      }
    }
  }
  __syncthreads();

  // coalesced stores: Q 64x96 (768 ushort8), KV 64x192 (1536 ushort8)
  #pragma unroll
  for (int it = 0; it < 3; it++) {
    int c = tid + it * 256;
    int row = c / 12, cc = (c % 12) * 8;
    *(bf16x8*)(Qb + (size_t)(r0 + row) * 96 + cc) = *(const bf16x8*)&qo[row * 104 + cc];
  }
  #pragma unroll
  for (int it = 0; it < 6; it++) {
    int c = tid + it * 256;
    int row = c / 24, cc = (c % 24) * 8;
    *(bf16x8*)(KVb + (size_t)(r0 + row) * 192 + cc) = *(const bf16x8*)&kvo[row * 200 + cc];
  }
}

// ---- fused attention + proj: block = 64 pixels x 12 heads -----------------
// attention result (64x192 bf16) stays in LDS and feeds the proj MFMA.
__global__ __launch_bounds__(256) void attnproj_kernel(
    const unsigned short* __restrict__ Qb, const unsigned short* __restrict__ KVb,
    const unsigned short* __restrict__ wp, const float* __restrict__ bp,
    float* __restrict__ Out)
{
  __shared__ unsigned short s_out[64 * 200];   // attention out tile, stride 200
  const int tid = threadIdx.x;
  const int bl0 = blockIdx.x * 64;

  // ---- attention phase: 768 (pixel,head) tasks, 3 per thread ----
  #pragma unroll
  for (int it = 0; it < 3; it++) {
    int task = it * 256 + tid;
    int n  = task % NH;
    int pl = task / NH;                        // local pixel 0..63
    int bl = bl0 + pl;
    int l  = bl % LPIX;
    int b  = bl / LPIX;
    int h2 = l / HW2, w2 = l - h2 * HW2;

    const unsigned short* qp = Qb + (size_t)bl * 192 + n * 16;
    float q[16];
    {
      unsigned short qd[16];
      *(uint4*)&qd[0] = *(const uint4*)(qp);
      *(uint4*)&qd[8] = *(const uint4*)(qp + 8);
      #pragma unroll
      for (int j = 0; j < 16; j++) q[j] = bf2f(qd[j]);
    }

    const unsigned short* kvb = KVb + (size_t)b * (LPIX * 384) + n * 16;

    float sc[9];
    int   nb[9];
    #pragma unroll
    for (int kk = 0; kk < 9; kk++) {
      int hh = h2 + kk / 3 - 1;
      int ww = w2 + kk % 3 - 1;
      bool ok = ((unsigned)hh < (unsigned)HW2) && ((unsigned)ww < (unsigned)HW2);
      nb[kk] = ok ? (hh * HW2 + ww) * 384 : -1;
      float s = 0.f;
      if (ok) {
        const unsigned short* kp = kvb + nb[kk];
        unsigned short kd[16];
        *(uint4*)&kd[0] = *(const uint4*)(kp);
        *(uint4*)&kd[8] = *(const uint4*)(kp + 8);
        #pragma unroll
        for (int j = 0; j < 16; j++) s = fmaf(q[j], bf2f(kd[j]), s);
      }
      sc[kk] = s;
    }

    float m = sc[0];
    #pragma unroll
    for (int kk = 1; kk < 9; kk++) m = fmaxf(m, sc[kk]);
    float ssum = 0.f;
    #pragma unroll
    for (int kk = 0; kk < 9; kk++) {
      float e = __expf(sc[kk] - m);
      sc[kk] = e;
      ssum += e;
    }

    float acc[16];
    #pragma unroll
    for (int j = 0; j < 16; j++) acc[j] = 0.f;
    #pragma unroll
    for (int kk = 0; kk < 9; kk++) {
      if (nb[kk] >= 0) {
        const unsigned short* vp = kvb + nb[kk] + 192;
        unsigned short vd[16];
        *(uint4*)&vd[0] = *(const uint4*)(vp);
        *(uint4*)&vd[8] = *(const uint4*)(vp + 8);
        float wgt = sc[kk];
        #pragma unroll
        for (int j = 0; j < 16; j++) acc[j] = fmaf(wgt, bf2f(vd[j]), acc[j]);
      }
    }
    float rinv = 1.f / ssum;
    unsigned short od[16];
    #pragma unroll
    for (int j = 0; j < 16; j++) od[j] = f2bf(acc[j] * rinv);
    unsigned short* op = s_out + pl * 200 + n * 16;
    *(uint4*)(op)     = *(uint4*)&od[0];
    *(uint4*)(op + 8) = *(uint4*)&od[8];
  }
  __syncthreads();

  // ---- proj phase: (64x192 bf16 LDS) x Wp^T + bp -> Out fp32 ----
  const int lane = tid & 63, w = tid >> 6;
  const int col  = lane & 15;
  const int koff = (lane >> 4) * 8;
  const int arow = 16 * w + (lane & 15);
  const int rbase = bl0 + 16 * w + 4 * (lane >> 4);

  bf16x8 af[6];
  #pragma unroll
  for (int kt = 0; kt < 6; kt++)
    af[kt] = *(const bf16x8*)&s_out[arow * 200 + koff + kt * 32];

  #pragma unroll
  for (int nt = 0; nt < 12; nt++) {
    const unsigned short* wrow = wp + (size_t)(nt * 16 + col) * 192 + koff;
    f32x4 acc = {0.f, 0.f, 0.f, 0.f};
    #pragma unroll
    for (int kt = 0; kt < 6; kt++) {
      bf16x8 bfr = *(const bf16x8*)(wrow + kt * 32);
      acc = __builtin_amdgcn_mfma_f32_16x16x32_bf16(af[kt], bfr, acc, 0, 0, 0);
    }
    int u = nt * 16 + col;
    float bias = bp[u];
    #pragma unroll
    for (int i = 0; i < 4; i++)
      Out[(size_t)(rbase + i) * 192 + u] = acc[i] + bias;
  }
}

extern "C" void kernel_launch(void* const* d_in, const int* in_sizes, int n_in,
                              void* d_out, int out_size, void* d_ws, size_t ws_size,
                              hipStream_t stream) {
  const float* x   = (const float*)d_in[0];
  const float* Wq  = (const float*)d_in[1];
  const float* bq  = (const float*)d_in[2];
  const float* Wkv = (const float*)d_in[3];
  const float* bkv = (const float*)d_in[4];
  const float* Wp  = (const float*)d_in[5];
  const float* bp  = (const float*)d_in[6];
  const float* fqr = (const float*)d_in[7];
  const float* fkr = (const float*)d_in[8];
  const float* fvr = (const float*)d_in[9];

  char* ws = (char*)d_ws;
  unsigned short* Qb   = (unsigned short*)ws;                 // 14,155,776 B
  unsigned short* KVb  = (unsigned short*)(ws + 14155776);    // 28,311,552 B
  unsigned short* wqb  = (unsigned short*)(ws + 42467328);    //     18,432 B
  unsigned short* wkvb = (unsigned short*)(ws + 42485760);    //     36,864 B
  unsigned short* wpb  = (unsigned short*)(ws + 42522624);    //     73,728 B

  cvt_w_kernel<<<dim3(252), dim3(256), 0, stream>>>(Wq, Wkv, Wp, wqb, wkvb, wpb);

  qkv_gemm<<<dim3(1152), dim3(256), 0, stream>>>(
      x, wqb, wkvb, bq, bkv, fqr, fkr, fvr, Qb, KVb);

  attnproj_kernel<<<dim3(576), dim3(256), 0, stream>>>(
      Qb, KVb, wpb, bp, (float*)d_out);
}